// Round 6
// baseline (192.929 us; speedup 1.0000x reference)
//
#include <hip/hip_runtime.h>
#include <stdint.h>
#include <math.h>

typedef unsigned short u16;
typedef unsigned int u32;
typedef __bf16 bf16x8 __attribute__((ext_vector_type(8)));
typedef unsigned short u16x8 __attribute__((ext_vector_type(8)));
typedef unsigned short u16x4 __attribute__((ext_vector_type(4)));
typedef float f32x4 __attribute__((ext_vector_type(4)));
typedef float f32x16 __attribute__((ext_vector_type(16)));

#define MFMA16(a, b, c) __builtin_amdgcn_mfma_f32_16x16x32_bf16((a), (b), (c), 0, 0, 0)
#define MFMA32(a, b, c) __builtin_amdgcn_mfma_f32_32x32x16_bf16((a), (b), (c), 0, 0, 0)

__device__ __forceinline__ u16 f2b(float f) {
    union { unsigned int i; float f; } v; v.f = f;
    unsigned int r = (v.i + 0x7FFFu + ((v.i >> 16) & 1u)) >> 16;
    return (u16)r;
}
// packed f32x2 -> bf16x2 (RNE), 1 VALU instruction (T12 recipe)
__device__ __forceinline__ u32 cvtpk(float lo, float hi) {
    u32 r; asm("v_cvt_pk_bf16_f32 %0, %1, %2" : "=v"(r) : "v"(lo), "v"(hi));
    return r;
}

constexpr int N = 4096;
constexpr int Cc = 128;
constexpr int Fc = 128;
constexpr int BATCH = 4;
constexpr int NT = N / 128;     // 32 key tiles of 128 keys

constexpr int XS_STRIDE = 136;
constexpr int WT_STRIDE = 136;
constexpr int OM_STRIDE = 130;  // epilogue merge rows (f32): 2-way banks = free

// Q projection scale: (1/sqrt(128)) * log2(e)  -> softmax runs in exp2 domain
#define QSCALE 0.12751744750f

// ---------------------------------------------------------------------------
// W pre-transpose: Wt[which][f][c] (bf16). grid 3 x 256.
// ---------------------------------------------------------------------------
__global__ __launch_bounds__(256) void wtrans_kernel(
    const float* __restrict__ Wq, const float* __restrict__ Wk,
    const float* __restrict__ Wv, u16* __restrict__ WtG)
{
    __shared__ __align__(16) u16 Wl[128 * 132];  // [c][f]
    const int tid = threadIdx.x;
    const int which = blockIdx.x;
    const float* W = which == 0 ? Wq : (which == 1 ? Wk : Wv);
#pragma unroll
    for (int it = 0; it < 16; ++it) {
        int idx4 = tid + it * 256; int e0 = idx4 * 4;
        int c = e0 >> 7, f = e0 & 127;
        float4 wv = *(const float4*)(W + e0);
        u16x4 h; h[0] = f2b(wv.x); h[1] = f2b(wv.y); h[2] = f2b(wv.z); h[3] = f2b(wv.w);
        *(u16x4*)&Wl[c * 132 + f] = h;
    }
    __syncthreads();
    u16* out = WtG + which * 16384;
#pragma unroll
    for (int it = 0; it < 8; ++it) {
        int idx8 = tid + it * 256; int e0 = idx8 * 8;
        int f = e0 >> 7, c = e0 & 127;
        u16x8 h;
#pragma unroll
        for (int j = 0; j < 8; ++j) h[j] = Wl[(c + j) * 132 + f];
        *(u16x8*)(out + e0) = h;
    }
}

// ---------------------------------------------------------------------------
// Projection (fp32 X, bf16 Wt -> bf16 workspace). grid (64,3,4) x 256.
// Q: linear [b][m][f], pre-scaled by QSCALE.
// K: FRAGMENT-MAJOR  K_fm[b][kgrp=key>>5][kk=c>>4][lane][8]
//      lane = ((c>>3)&1)*32 + (key&31), elem j = c&7
// Vt: FRAGMENT-MAJOR V_fm[b][kgrp=key>>5][(ch>>5)*2 + ((key>>4)&1)][lane][8]
//      lane = ((key>>3)&1)*32 + (ch&31), elem j = key&7
// so the attn kernel's per-wave fragment loads are base + lane*16B
// (fully coalesced 1 KB streams straight from L2 into registers).
// ---------------------------------------------------------------------------
__global__ __launch_bounds__(256) void proj_kernel(
    const float* __restrict__ q_in, const float* __restrict__ kv_in,
    const u16* __restrict__ WtG,
    const float* __restrict__ bq, const float* __restrict__ bk,
    const float* __restrict__ bv,
    u16* __restrict__ Qw, u16* __restrict__ Kw, u16* __restrict__ Vtw)
{
    __shared__ __align__(16) u16 Xs[64 * XS_STRIDE];   // [m][c] bf16
    __shared__ __align__(16) u16 Wt[128 * WT_STRIDE];  // [f][c] bf16

    const int tid = threadIdx.x;
    const int which = blockIdx.y;
    const int b = blockIdx.z;
    const int m0 = blockIdx.x * 64;

    const float* X = (which == 0 ? q_in : kv_in) + ((size_t)b * N + m0) * Cc;
    const u16* Wsrc = WtG + which * 16384;
    const float* bias = which == 0 ? bq : (which == 1 ? bk : bv);

#pragma unroll
    for (int it = 0; it < 8; ++it) {
        int idx4 = tid + it * 256; int e0 = idx4 * 4;
        int r = e0 >> 7, c = e0 & 127;
        float4 xv = *(const float4*)(X + e0);
        u16x4 h; h[0] = f2b(xv.x); h[1] = f2b(xv.y); h[2] = f2b(xv.z); h[3] = f2b(xv.w);
        *(u16x4*)&Xs[r * XS_STRIDE + c] = h;
    }
#pragma unroll
    for (int it = 0; it < 8; ++it) {
        int idx8 = tid + it * 256; int e0 = idx8 * 8;
        int f = e0 >> 7, c = e0 & 127;
        *(u16x8*)&Wt[f * WT_STRIDE + c] = *(const u16x8*)(Wsrc + e0);
    }
    __syncthreads();

    const int lane = tid & 63;
    const int w = tid >> 6;
    const int n16 = lane & 15;
    const int quad = lane >> 4;

    if (which < 2) {
        bf16x8 ax[4];
#pragma unroll
        for (int kk = 0; kk < 4; ++kk)
            ax[kk] = *(const bf16x8*)&Xs[(w * 16 + n16) * XS_STRIDE + kk * 32 + quad * 8];
        const float scale = (which == 0) ? QSCALE : 1.0f;
#pragma unroll
        for (int ft = 0; ft < 8; ++ft) {
            f32x4 acc = {0.f, 0.f, 0.f, 0.f};
#pragma unroll
            for (int kk = 0; kk < 4; ++kk) {
                bf16x8 bw = *(const bf16x8*)&Wt[(ft * 16 + n16) * WT_STRIDE + kk * 32 + quad * 8];
                acc = MFMA16(ax[kk], bw, acc);
            }
            float bias_f = bias[ft * 16 + n16];
#pragma unroll
            for (int r = 0; r < 4; ++r) {
                int row = m0 + w * 16 + quad * 4 + r;   // token index
                int f = ft * 16 + n16;                   // channel
                u16 val = f2b((acc[r] + bias_f) * scale);
                if (which == 0) {
                    Qw[((size_t)b * N + row) * Fc + f] = val;
                } else {
                    // K fragment-major
                    int kgrp = row >> 5, l31r = row & 31;
                    int kk2 = f >> 4, hig = (f >> 3) & 1, jj = f & 7;
                    Kw[((size_t)b * 1024 + kgrp * 8 + kk2) * 512
                       + (hig * 32 + l31r) * 8 + jj] = val;
                }
            }
        }
    } else {
#pragma unroll
        for (int ft2 = 0; ft2 < 2; ++ft2) {
            int ftg = w * 2 + ft2;
            bf16x8 aw[4];
#pragma unroll
            for (int kk = 0; kk < 4; ++kk)
                aw[kk] = *(const bf16x8*)&Wt[(ftg * 16 + n16) * WT_STRIDE + kk * 32 + quad * 8];
            float bias4[4];
#pragma unroll
            for (int r = 0; r < 4; ++r) bias4[r] = bias[ftg * 16 + quad * 4 + r];
#pragma unroll
            for (int nt = 0; nt < 4; ++nt) {
                f32x4 acc = {0.f, 0.f, 0.f, 0.f};
#pragma unroll
                for (int kk = 0; kk < 4; ++kk) {
                    bf16x8 bx = *(const bf16x8*)&Xs[(nt * 16 + n16) * XS_STRIDE + kk * 32 + quad * 8];
                    acc = MFMA16(aw[kk], bx, acc);
                }
#pragma unroll
                for (int r = 0; r < 4; ++r) {
                    int fg = ftg * 16 + quad * 4 + r;   // channel
                    int rowg = m0 + nt * 16 + n16;      // key
                    // V fragment-major
                    int kgrp = rowg >> 5, ks = (rowg >> 4) & 1;
                    int hig = (rowg >> 3) & 1, jj = rowg & 7;
                    int cb = fg >> 5, l31r = fg & 31;
                    Vtw[((size_t)b * 1024 + kgrp * 8 + cb * 2 + ks) * 512
                        + (hig * 32 + l31r) * 8 + jj] = f2b(acc[r] + bias4[r]);
                }
            }
        }
    }
}

// ---------------------------------------------------------------------------
// Flash attention, 32x32 MFMA, in-register P (cvt_pk + permlane32_swap).
// K and V stream DIRECTLY from L2 into registers via fragment-major layout.
// Deep pipeline: V double-buffered (~1.5 tiles cover), K prefetch distance 2,
// QK accumulator split into 2 chains. No LDS / no barriers in the main loop.
// 512 threads = 8 waves = 2 q-groups(32 rows) x 4 key-groups(32 keys).
// grid (64, 4), 1 block/CU. XCD-swizzled: one batch per XCD (K+V L2-local).
// ---------------------------------------------------------------------------
__global__ __launch_bounds__(512, 2) void attn_kernel(
    const u16* __restrict__ Qw, const u16* __restrict__ Kw,
    const u16* __restrict__ Vtw, float* __restrict__ out)
{
    __shared__ __align__(16) char smem[134144];

    const int tid = threadIdx.x;
    // XCD-aware remap: blocks with equal (id&7) share a batch.
    const int id = blockIdx.x + 64 * blockIdx.y;
    const int b = (id >> 1) & 3;
    const int q0 = (((id & 1) << 5) + (id >> 3)) << 6;

    const int lane = tid & 63;
    const int w = tid >> 6;      // 0..7
    const int kg = w & 3;        // 32-key group within 128-key tile
    const int qg = w >> 2;       // 32-row q group within 64-row block
    const int l31 = lane & 31;
    const int hi = lane >> 5;

    // ---- Q fragments (B-operand of swapped QK^T), held for whole loop
    bf16x8 aq[8];
    {
        const u16* qp = Qw + ((size_t)b * N + q0 + qg * 32 + l31) * Cc + hi * 8;
#pragma unroll
        for (int kk = 0; kk < 8; ++kk) aq[kk] = *(const bf16x8*)(qp + kk * 16);
    }

    // fragment-major bases for this wave's key-group (+ lane offset)
    // per-tile stride = 4 kgrp * 8 groups * 512 u16 = 16384 u16
    const u16* const kfb = Kw + ((size_t)b * 1024 + kg * 8) * 512 + lane * 8;
    const u16* const vfb = Vtw + ((size_t)b * 1024 + kg * 8) * 512 + lane * 8;

    f32x16 o[4];
#pragma unroll
    for (int cb = 0; cb < 4; ++cb)
#pragma unroll
        for (int i = 0; i < 16; ++i) o[cb][i] = 0.f;
    float lloc = 0.f;

    bf16x8 kf0[8], kf1[8], vf0[8], vf1[8];

    auto LOADK = [&](bf16x8* kf, int t) {
        const u16* p = kfb + (size_t)t * 16384;
#pragma unroll
        for (int kk = 0; kk < 8; ++kk)
            kf[kk] = *(const bf16x8*)(p + kk * 512);
    };
    auto LOADV = [&](bf16x8* vf, int t) {
        const u16* p = vfb + (size_t)t * 16384;
#pragma unroll
        for (int g = 0; g < 8; ++g)
            vf[g] = *(const bf16x8*)(p + g * 512);   // g = cb*2+ks
    };

    // One tile step. kfc/vfc: current tile's fragments. kfn<-tk (K prefetch,
    // issued right after QK releases kfc). vfn<-tv (V prefetch, issued first:
    // ~1.5 tiles of latency cover before its PV consumes it).
    auto STEP = [&](const bf16x8* kfc, const bf16x8* vfc,
                    bf16x8* kfn, int tk, bf16x8* vfn, int tv) {
        if (tv < NT) LOADV(vfn, tv);
        // S^T = K . Q^T over this wave's 32 keys: D[key][q], col=q=l31.
        // Two interleaved accumulator chains halve the serial MFMA latency.
        f32x16 sa, sb;
#pragma unroll
        for (int i = 0; i < 16; ++i) { sa[i] = 0.f; sb[i] = 0.f; }
        __builtin_amdgcn_s_setprio(1);
#pragma unroll
        for (int kk = 0; kk < 4; ++kk) {
            sa = MFMA32(kfc[2 * kk + 0], aq[2 * kk + 0], sa);
            sb = MFMA32(kfc[2 * kk + 1], aq[2 * kk + 1], sb);
        }
        __builtin_amdgcn_s_setprio(0);
        if (tk < NT) LOADK(kfn, tk);   // kfc fully consumed by the MFMAs above
        f32x16 st = sa + sb;
        // p = 2^s (Q pre-scaled by log2e); reg i = key (i&3)+8*(i>>2)+4*hi (+16 for i>=8)
        float p[16];
#pragma unroll
        for (int i = 0; i < 16; ++i) p[i] = exp2f(st[i]);
        lloc += ((((p[0] + p[1]) + (p[2] + p[3])) + ((p[4] + p[5]) + (p[6] + p[7])))
               + (((p[8] + p[9]) + (p[10] + p[11])) + ((p[12] + p[13]) + (p[14] + p[15]))));
        // pack bf16 pairs + permlane32_swap -> PV B-fragments (P^T), no LDS
        bf16x8 pb[2];
#pragma unroll
        for (int ks = 0; ks < 2; ++ks) {
            u32 a0 = cvtpk(p[ks * 8 + 0], p[ks * 8 + 1]);
            u32 a1 = cvtpk(p[ks * 8 + 2], p[ks * 8 + 3]);
            u32 a2 = cvtpk(p[ks * 8 + 4], p[ks * 8 + 5]);
            u32 a3 = cvtpk(p[ks * 8 + 6], p[ks * 8 + 7]);
            auto s02 = __builtin_amdgcn_permlane32_swap(a0, a2, false, false);
            auto s13 = __builtin_amdgcn_permlane32_swap(a1, a3, false, false);
            union { u32 u[4]; bf16x8 v; } bb;
            bb.u[0] = s02[0]; bb.u[1] = s13[0]; bb.u[2] = s02[1]; bb.u[3] = s13[1];
            pb[ks] = bb.v;
        }
        // O^T += Vt . P^T : D[ch][q], A = V fragments (registers)
        __builtin_amdgcn_s_setprio(1);
#pragma unroll
        for (int cb = 0; cb < 4; ++cb) {
            o[cb] = MFMA32(vfc[cb * 2 + 0], pb[0], o[cb]);
            o[cb] = MFMA32(vfc[cb * 2 + 1], pb[1], o[cb]);
        }
        __builtin_amdgcn_s_setprio(0);
    };

    LOADK(kf0, 0);
    LOADV(vf0, 0);
    LOADK(kf1, 1);
    for (int t = 0; t < NT; t += 2) {
        // even: compute (kf0, vf0); prefetch vf1<-t+1, kf0<-t+2
        STEP(kf0, vf0, kf0, t + 2, vf1, t + 1);
        // odd:  compute (kf1, vf1); prefetch vf0<-t+2, kf1<-t+3
        STEP(kf1, vf1, kf1, t + 3, vf0, t + 2);
    }

    // ---- atomic-free merge: all 8 waves dump to private slot, then reduce
    float lv = lloc + __shfl_xor(lloc, 32);   // full l-partial for q=l31, this kg

    float* const Om = (float*)smem;            // [4 kg][64 q][OM_STRIDE] f32
    float* const Lm = (float*)(smem + 4 * 64 * OM_STRIDE * 4);  // [4 kg][64 q]

    const int qrow_w = qg * 32 + l31;          // 0..63 within block
    const int crow0 = 4 * hi;
    {
        float* dst = Om + (size_t)(kg * 64 + qrow_w) * OM_STRIDE;
#pragma unroll
        for (int cb = 0; cb < 4; ++cb)
#pragma unroll
            for (int i = 0; i < 16; ++i) {
                int ch = cb * 32 + (i & 3) + 8 * (i >> 2) + crow0;
                dst[ch] = o[cb][i];
            }
        if (hi == 0) Lm[kg * 64 + qrow_w] = lv;
    }
    __syncthreads();

    const int qrow = tid >> 3;                // 0..63
    const int ch0 = (tid & 7) * 16;
    const float lsum = Lm[qrow] + Lm[64 + qrow] + Lm[128 + qrow] + Lm[192 + qrow];
    const float linv = 1.0f / lsum;
    float* op = out + ((size_t)b * N + q0 + qrow) * Fc + ch0;
#pragma unroll
    for (int j4 = 0; j4 < 4; ++j4) {
        f32x4 v;
#pragma unroll
        for (int jj = 0; jj < 4; ++jj) {
            int ch = ch0 + j4 * 4 + jj;
            float s = Om[(size_t)(0 * 64 + qrow) * OM_STRIDE + ch]
                    + Om[(size_t)(1 * 64 + qrow) * OM_STRIDE + ch]
                    + Om[(size_t)(2 * 64 + qrow) * OM_STRIDE + ch]
                    + Om[(size_t)(3 * 64 + qrow) * OM_STRIDE + ch];
            v[jj] = s * linv;
        }
        *(f32x4*)(op + j4 * 4) = v;
    }
}

extern "C" void kernel_launch(void* const* d_in, const int* in_sizes, int n_in,
                              void* d_out, int out_size, void* d_ws, size_t ws_size,
                              hipStream_t stream) {
    (void)in_sizes; (void)n_in; (void)out_size; (void)ws_size;
    const float* q_in  = (const float*)d_in[0];
    const float* kv_in = (const float*)d_in[1];
    const float* Wq = (const float*)d_in[2];
    const float* bq = (const float*)d_in[3];
    const float* Wk = (const float*)d_in[4];
    const float* bk = (const float*)d_in[5];
    const float* Wv = (const float*)d_in[6];
    const float* bv = (const float*)d_in[7];

    const size_t qkv = (size_t)BATCH * N * Fc;
    u16* Qw  = (u16*)d_ws;          // [b][m][f] bf16, pre-scaled by QSCALE
    u16* Kw  = Qw + qkv;            // fragment-major K (1 MB/batch)
    u16* Vtw = Kw + qkv;            // fragment-major V^T (1 MB/batch)
    u16* WtG = Vtw + qkv;           // [3][f][c] bf16 pre-transposed weights

    wtrans_kernel<<<dim3(3), dim3(256), 0, stream>>>(Wq, Wk, Wv, WtG);
    proj_kernel<<<dim3(64, 3, BATCH), dim3(256), 0, stream>>>(
        q_in, kv_in, WtG, bq, bk, bv, Qw, Kw, Vtw);
    attn_kernel<<<dim3(64, BATCH), dim3(512), 0, stream>>>(
        Qw, Kw, Vtw, (float*)d_out);
}

// Round 7
// 137.939 us; speedup vs baseline: 1.3987x; 1.3987x over previous
//
#include <hip/hip_runtime.h>
#include <stdint.h>
#include <math.h>

typedef unsigned short u16;
typedef unsigned int u32;
typedef __bf16 bf16x8 __attribute__((ext_vector_type(8)));
typedef unsigned short u16x8 __attribute__((ext_vector_type(8)));
typedef unsigned short u16x4 __attribute__((ext_vector_type(4)));
typedef float f32x4 __attribute__((ext_vector_type(4)));
typedef float f32x16 __attribute__((ext_vector_type(16)));

#define MFMA16(a, b, c) __builtin_amdgcn_mfma_f32_16x16x32_bf16((a), (b), (c), 0, 0, 0)
#define MFMA32(a, b, c) __builtin_amdgcn_mfma_f32_32x32x16_bf16((a), (b), (c), 0, 0, 0)

__device__ __forceinline__ u16 f2b(float f) {
    union { unsigned int i; float f; } v; v.f = f;
    unsigned int r = (v.i + 0x7FFFu + ((v.i >> 16) & 1u)) >> 16;
    return (u16)r;
}
// packed f32x2 -> bf16x2 (RNE), 1 VALU instruction (T12 recipe)
__device__ __forceinline__ u32 cvtpk(float lo, float hi) {
    u32 r; asm("v_cvt_pk_bf16_f32 %0, %1, %2" : "=v"(r) : "v"(lo), "v"(hi));
    return r;
}
// async global->LDS, 16B per lane. HW dest = wave-uniform base + lane*16.
__device__ __forceinline__ void gload16(const void* g, void* l) {
    __builtin_amdgcn_global_load_lds(
        (const __attribute__((address_space(1))) u32*)g,
        (__attribute__((address_space(3))) u32*)l, 16, 0, 0);
}

constexpr int N = 4096;
constexpr int Cc = 128;
constexpr int Fc = 128;
constexpr int BATCH = 4;
constexpr int NT = N / 128;     // 32 key tiles of 128 keys

constexpr int XS_STRIDE = 136;
constexpr int WT_STRIDE = 136;
constexpr int OM_STRIDE = 130;  // epilogue merge rows (f32): 2-way banks = free

// Q projection scale: (1/sqrt(128)) * log2(e)  -> softmax runs in exp2 domain
#define QSCALE 0.12751744750f

// ---------------------------------------------------------------------------
// W pre-transpose: Wt[which][f][c] (bf16). grid 3 x 256.
// ---------------------------------------------------------------------------
__global__ __launch_bounds__(256) void wtrans_kernel(
    const float* __restrict__ Wq, const float* __restrict__ Wk,
    const float* __restrict__ Wv, u16* __restrict__ WtG)
{
    __shared__ __align__(16) u16 Wl[128 * 132];  // [c][f]
    const int tid = threadIdx.x;
    const int which = blockIdx.x;
    const float* W = which == 0 ? Wq : (which == 1 ? Wk : Wv);
#pragma unroll
    for (int it = 0; it < 16; ++it) {
        int idx4 = tid + it * 256; int e0 = idx4 * 4;
        int c = e0 >> 7, f = e0 & 127;
        float4 wv = *(const float4*)(W + e0);
        u16x4 h; h[0] = f2b(wv.x); h[1] = f2b(wv.y); h[2] = f2b(wv.z); h[3] = f2b(wv.w);
        *(u16x4*)&Wl[c * 132 + f] = h;
    }
    __syncthreads();
    u16* out = WtG + which * 16384;
#pragma unroll
    for (int it = 0; it < 8; ++it) {
        int idx8 = tid + it * 256; int e0 = idx8 * 8;
        int f = e0 >> 7, c = e0 & 127;
        u16x8 h;
#pragma unroll
        for (int j = 0; j < 8; ++j) h[j] = Wl[(c + j) * 132 + f];
        *(u16x8*)(out + e0) = h;
    }
}

// ---------------------------------------------------------------------------
// Projection (fp32 X, bf16 Wt -> bf16 workspace). grid (64,3,4) x 256.
// Q: linear [b][m][f], pre-scaled by QSCALE.
// K: FRAGMENT-MAJOR  K_fm[b][kgrp=key>>5][kk=c>>4][lane][8]
//      lane = ((c>>3)&1)*32 + (key&31), elem j = c&7
// Vt: FRAGMENT-MAJOR V_fm[b][kgrp=key>>5][(ch>>5)*2 + ((key>>4)&1)][lane][8]
//      lane = ((key>>3)&1)*32 + (ch&31), elem j = key&7
// Attn reads both as base + lane*16B (coalesced); V tile (32 KB) is
// CONTIGUOUS -> global_load_lds with linear dest, conflict-free readback.
// ---------------------------------------------------------------------------
__global__ __launch_bounds__(256) void proj_kernel(
    const float* __restrict__ q_in, const float* __restrict__ kv_in,
    const u16* __restrict__ WtG,
    const float* __restrict__ bq, const float* __restrict__ bk,
    const float* __restrict__ bv,
    u16* __restrict__ Qw, u16* __restrict__ Kw, u16* __restrict__ Vtw)
{
    __shared__ __align__(16) u16 Xs[64 * XS_STRIDE];   // [m][c] bf16
    __shared__ __align__(16) u16 Wt[128 * WT_STRIDE];  // [f][c] bf16

    const int tid = threadIdx.x;
    const int which = blockIdx.y;
    const int b = blockIdx.z;
    const int m0 = blockIdx.x * 64;

    const float* X = (which == 0 ? q_in : kv_in) + ((size_t)b * N + m0) * Cc;
    const u16* Wsrc = WtG + which * 16384;
    const float* bias = which == 0 ? bq : (which == 1 ? bk : bv);

#pragma unroll
    for (int it = 0; it < 8; ++it) {
        int idx4 = tid + it * 256; int e0 = idx4 * 4;
        int r = e0 >> 7, c = e0 & 127;
        float4 xv = *(const float4*)(X + e0);
        u16x4 h; h[0] = f2b(xv.x); h[1] = f2b(xv.y); h[2] = f2b(xv.z); h[3] = f2b(xv.w);
        *(u16x4*)&Xs[r * XS_STRIDE + c] = h;
    }
#pragma unroll
    for (int it = 0; it < 8; ++it) {
        int idx8 = tid + it * 256; int e0 = idx8 * 8;
        int f = e0 >> 7, c = e0 & 127;
        *(u16x8*)&Wt[f * WT_STRIDE + c] = *(const u16x8*)(Wsrc + e0);
    }
    __syncthreads();

    const int lane = tid & 63;
    const int w = tid >> 6;
    const int n16 = lane & 15;
    const int quad = lane >> 4;

    if (which < 2) {
        bf16x8 ax[4];
#pragma unroll
        for (int kk = 0; kk < 4; ++kk)
            ax[kk] = *(const bf16x8*)&Xs[(w * 16 + n16) * XS_STRIDE + kk * 32 + quad * 8];
        const float scale = (which == 0) ? QSCALE : 1.0f;
#pragma unroll
        for (int ft = 0; ft < 8; ++ft) {
            f32x4 acc = {0.f, 0.f, 0.f, 0.f};
#pragma unroll
            for (int kk = 0; kk < 4; ++kk) {
                bf16x8 bw = *(const bf16x8*)&Wt[(ft * 16 + n16) * WT_STRIDE + kk * 32 + quad * 8];
                acc = MFMA16(ax[kk], bw, acc);
            }
            float bias_f = bias[ft * 16 + n16];
#pragma unroll
            for (int r = 0; r < 4; ++r) {
                int row = m0 + w * 16 + quad * 4 + r;   // token index
                int f = ft * 16 + n16;                   // channel
                u16 val = f2b((acc[r] + bias_f) * scale);
                if (which == 0) {
                    Qw[((size_t)b * N + row) * Fc + f] = val;
                } else {
                    // K fragment-major
                    int kgrp = row >> 5, l31r = row & 31;
                    int kk2 = f >> 4, hig = (f >> 3) & 1, jj = f & 7;
                    Kw[((size_t)b * 1024 + kgrp * 8 + kk2) * 512
                       + (hig * 32 + l31r) * 8 + jj] = val;
                }
            }
        }
    } else {
#pragma unroll
        for (int ft2 = 0; ft2 < 2; ++ft2) {
            int ftg = w * 2 + ft2;
            bf16x8 aw[4];
#pragma unroll
            for (int kk = 0; kk < 4; ++kk)
                aw[kk] = *(const bf16x8*)&Wt[(ftg * 16 + n16) * WT_STRIDE + kk * 32 + quad * 8];
            float bias4[4];
#pragma unroll
            for (int r = 0; r < 4; ++r) bias4[r] = bias[ftg * 16 + quad * 4 + r];
#pragma unroll
            for (int nt = 0; nt < 4; ++nt) {
                f32x4 acc = {0.f, 0.f, 0.f, 0.f};
#pragma unroll
                for (int kk = 0; kk < 4; ++kk) {
                    bf16x8 bx = *(const bf16x8*)&Xs[(nt * 16 + n16) * XS_STRIDE + kk * 32 + quad * 8];
                    acc = MFMA16(aw[kk], bx, acc);
                }
#pragma unroll
                for (int r = 0; r < 4; ++r) {
                    int fg = ftg * 16 + quad * 4 + r;   // channel
                    int rowg = m0 + nt * 16 + n16;      // key
                    // V fragment-major
                    int kgrp = rowg >> 5, ks = (rowg >> 4) & 1;
                    int hig = (rowg >> 3) & 1, jj = rowg & 7;
                    int cb = fg >> 5, l31r = fg & 31;
                    Vtw[((size_t)b * 1024 + kgrp * 8 + cb * 2 + ks) * 512
                        + (hig * 32 + l31r) * 8 + jj] = f2b(acc[r] + bias4[r]);
                }
            }
        }
    }
}

// ---------------------------------------------------------------------------
// Flash attention, 32x32 MFMA, in-register P (cvt_pk + permlane32_swap).
// K: register double-buffer streamed from L2 (frag-major, coalesced,
//    prefetch distance = 1 full tile).
// V: LDS double-buffer via global_load_lds of the CONTIGUOUS frag-major
//    tile (linear dest; readback = base+lane*16B, conflict-free), staged
//    one full tile ahead -> full latency cover behind the tile barrier.
// 512 threads = 8 waves = 2 q-groups(32 rows) x 4 key-groups(32 keys).
// grid (64, 4), 1 block/CU. XCD-swizzled: one batch per XCD (K+V L2-local).
// ---------------------------------------------------------------------------
__global__ __launch_bounds__(512, 2) void attn_kernel(
    const u16* __restrict__ Qw, const u16* __restrict__ Kw,
    const u16* __restrict__ Vtw, float* __restrict__ out)
{
    __shared__ __align__(16) char smem[134144];
    u16* const Vs0 = (u16*)smem;              // 32 KB frag-major V tile
    u16* const Vs1 = (u16*)(smem + 32768);    // (epilogue aliases smem)

    const int tid = threadIdx.x;
    // XCD-aware remap: blocks with equal (id&7) share a batch.
    const int id = blockIdx.x + 64 * blockIdx.y;
    const int b = (id >> 1) & 3;
    const int q0 = (((id & 1) << 5) + (id >> 3)) << 6;

    const int lane = tid & 63;
    const int w = tid >> 6;      // 0..7
    const int kg = w & 3;        // 32-key group within 128-key tile
    const int qg = w >> 2;       // 32-row q group within 64-row block
    const int l31 = lane & 31;
    const int hi = lane >> 5;

    // ---- Q fragments (B-operand of swapped QK^T), held for whole loop
    bf16x8 aq[8];
    {
        const u16* qp = Qw + ((size_t)b * N + q0 + qg * 32 + l31) * Cc + hi * 8;
#pragma unroll
        for (int kk = 0; kk < 8; ++kk) aq[kk] = *(const bf16x8*)(qp + kk * 16);
    }

    // fragment-major bases; per-tile stride = 4 kgrp * 8 grp * 512 = 16384 u16
    const u16* const kfb = Kw + ((size_t)b * 1024 + kg * 8) * 512 + lane * 8;
    const u16* const Vtile = Vtw + (size_t)b * 1024 * 512;
    // this wave's V read offset inside the staged tile (u16 units)
    const int vro = kg * 4096 + lane * 8;

    f32x16 o[4];
#pragma unroll
    for (int cb = 0; cb < 4; ++cb)
#pragma unroll
        for (int i = 0; i < 16; ++i) o[cb][i] = 0.f;
    float lloc = 0.f;

    bf16x8 kf0[8], kf1[8];

    int ci[4];
#pragma unroll
    for (int it = 0; it < 4; ++it) ci[it] = tid + it * 512;

    auto STAGE_V = [&](u16* vd, int t) {
        const u16* src = Vtile + (size_t)t * 16384;   // contiguous 32 KB tile
#pragma unroll
        for (int it = 0; it < 4; ++it)
            gload16(src + ci[it] * 8, vd + ci[it] * 8);
    };
    auto LOADK = [&](bf16x8* kf, int t) {
        const u16* p = kfb + (size_t)t * 16384;
#pragma unroll
        for (int kk = 0; kk < 8; ++kk)
            kf[kk] = *(const bf16x8*)(p + kk * 512);
    };

    auto COMPUTE = [&](const bf16x8* kf, const u16* Vsb) {
        // S^T = K . Q^T over this wave's 32 keys: D[key][q], col=q=l31
        f32x16 st;
#pragma unroll
        for (int i = 0; i < 16; ++i) st[i] = 0.f;
        __builtin_amdgcn_s_setprio(1);
#pragma unroll
        for (int kk = 0; kk < 8; ++kk)
            st = MFMA32(kf[kk], aq[kk], st);
        __builtin_amdgcn_s_setprio(0);
        // p = 2^s (Q pre-scaled by log2e); reg i = key (i&3)+8*(i>>2)+4*hi (+16 for i>=8)
        float p[16];
#pragma unroll
        for (int i = 0; i < 16; ++i) p[i] = exp2f(st[i]);
        lloc += ((((p[0] + p[1]) + (p[2] + p[3])) + ((p[4] + p[5]) + (p[6] + p[7])))
               + (((p[8] + p[9]) + (p[10] + p[11])) + ((p[12] + p[13]) + (p[14] + p[15]))));
        // pack bf16 pairs + permlane32_swap -> PV B-fragments (P^T), no LDS
        bf16x8 pb[2];
#pragma unroll
        for (int ks = 0; ks < 2; ++ks) {
            u32 a0 = cvtpk(p[ks * 8 + 0], p[ks * 8 + 1]);
            u32 a1 = cvtpk(p[ks * 8 + 2], p[ks * 8 + 3]);
            u32 a2 = cvtpk(p[ks * 8 + 4], p[ks * 8 + 5]);
            u32 a3 = cvtpk(p[ks * 8 + 6], p[ks * 8 + 7]);
            auto s02 = __builtin_amdgcn_permlane32_swap(a0, a2, false, false);
            auto s13 = __builtin_amdgcn_permlane32_swap(a1, a3, false, false);
            union { u32 u[4]; bf16x8 v; } bb;
            bb.u[0] = s02[0]; bb.u[1] = s13[0]; bb.u[2] = s02[1]; bb.u[3] = s13[1];
            pb[ks] = bb.v;
        }
        // O^T += Vt . P^T : D[ch][q]; A = contiguous b128 reads of staged V
        __builtin_amdgcn_s_setprio(1);
#pragma unroll
        for (int cb = 0; cb < 4; ++cb) {
            bf16x8 av0 = *(const bf16x8*)(Vsb + vro + (cb * 2 + 0) * 512);
            bf16x8 av1 = *(const bf16x8*)(Vsb + vro + (cb * 2 + 1) * 512);
            o[cb] = MFMA32(av0, pb[0], o[cb]);
            o[cb] = MFMA32(av1, pb[1], o[cb]);
        }
        __builtin_amdgcn_s_setprio(0);
    };

    STAGE_V(Vs0, 0);
    LOADK(kf0, 0);
    __syncthreads();                      // V(0) resident, K(0) in regs
    for (int t = 0; t < NT; t += 2) {
        STAGE_V(Vs1, t + 1);              // full tile of cover
        LOADK(kf1, t + 1);
        COMPUTE(kf0, Vs0);                // tile t
        __syncthreads();                  // V(t+1) resident; Vs0 free
        if (t + 2 < NT) { STAGE_V(Vs0, t + 2); LOADK(kf0, t + 2); }
        COMPUTE(kf1, Vs1);                // tile t+1
        __syncthreads();
    }

    // ---- atomic-free merge: all 8 waves dump to private slot, then reduce
    float lv = lloc + __shfl_xor(lloc, 32);   // full l-partial for q=l31, this kg

    float* const Om = (float*)smem;            // [4 kg][64 q][OM_STRIDE] f32
    float* const Lm = (float*)(smem + 4 * 64 * OM_STRIDE * 4);  // [4 kg][64 q]

    const int qrow_w = qg * 32 + l31;          // 0..63 within block
    const int crow0 = 4 * hi;
    {
        float* dst = Om + (size_t)(kg * 64 + qrow_w) * OM_STRIDE;
#pragma unroll
        for (int cb = 0; cb < 4; ++cb)
#pragma unroll
            for (int i = 0; i < 16; ++i) {
                int ch = cb * 32 + (i & 3) + 8 * (i >> 2) + crow0;
                dst[ch] = o[cb][i];
            }
        if (hi == 0) Lm[kg * 64 + qrow_w] = lv;
    }
    __syncthreads();

    const int qrow = tid >> 3;                // 0..63
    const int ch0 = (tid & 7) * 16;
    const float lsum = Lm[qrow] + Lm[64 + qrow] + Lm[128 + qrow] + Lm[192 + qrow];
    const float linv = 1.0f / lsum;
    float* op = out + ((size_t)b * N + q0 + qrow) * Fc + ch0;
#pragma unroll
    for (int j4 = 0; j4 < 4; ++j4) {
        f32x4 v;
#pragma unroll
        for (int jj = 0; jj < 4; ++jj) {
            int ch = ch0 + j4 * 4 + jj;
            float s = Om[(size_t)(0 * 64 + qrow) * OM_STRIDE + ch]
                    + Om[(size_t)(1 * 64 + qrow) * OM_STRIDE + ch]
                    + Om[(size_t)(2 * 64 + qrow) * OM_STRIDE + ch]
                    + Om[(size_t)(3 * 64 + qrow) * OM_STRIDE + ch];
            v[jj] = s * linv;
        }
        *(f32x4*)(op + j4 * 4) = v;
    }
}

extern "C" void kernel_launch(void* const* d_in, const int* in_sizes, int n_in,
                              void* d_out, int out_size, void* d_ws, size_t ws_size,
                              hipStream_t stream) {
    (void)in_sizes; (void)n_in; (void)out_size; (void)ws_size;
    const float* q_in  = (const float*)d_in[0];
    const float* kv_in = (const float*)d_in[1];
    const float* Wq = (const float*)d_in[2];
    const float* bq = (const float*)d_in[3];
    const float* Wk = (const float*)d_in[4];
    const float* bk = (const float*)d_in[5];
    const float* Wv = (const float*)d_in[6];
    const float* bv = (const float*)d_in[7];

    const size_t qkv = (size_t)BATCH * N * Fc;
    u16* Qw  = (u16*)d_ws;          // [b][m][f] bf16, pre-scaled by QSCALE
    u16* Kw  = Qw + qkv;            // fragment-major K (1 MB/batch)
    u16* Vtw = Kw + qkv;            // fragment-major V^T (1 MB/batch)
    u16* WtG = Vtw + qkv;           // [3][f][c] bf16 pre-transposed weights

    wtrans_kernel<<<dim3(3), dim3(256), 0, stream>>>(Wq, Wk, Wv, WtG);
    proj_kernel<<<dim3(64, 3, BATCH), dim3(256), 0, stream>>>(
        q_in, kv_in, WtG, bq, bk, bv, Qw, Kw, Vtw);
    attn_kernel<<<dim3(64, BATCH), dim3(512), 0, stream>>>(
        Qw, Kw, Vtw, (float*)d_out);
}

// Round 8
// 134.874 us; speedup vs baseline: 1.4304x; 1.0227x over previous
//
#include <hip/hip_runtime.h>
#include <stdint.h>
#include <math.h>

typedef unsigned short u16;
typedef unsigned int u32;
typedef __bf16 bf16x8 __attribute__((ext_vector_type(8)));
typedef unsigned short u16x8 __attribute__((ext_vector_type(8)));
typedef unsigned short u16x4 __attribute__((ext_vector_type(4)));
typedef float f32x4 __attribute__((ext_vector_type(4)));
typedef float f32x16 __attribute__((ext_vector_type(16)));

#define MFMA16(a, b, c) __builtin_amdgcn_mfma_f32_16x16x32_bf16((a), (b), (c), 0, 0, 0)
#define MFMA32(a, b, c) __builtin_amdgcn_mfma_f32_32x32x16_bf16((a), (b), (c), 0, 0, 0)

__device__ __forceinline__ u16 f2b(float f) {
    union { unsigned int i; float f; } v; v.f = f;
    unsigned int r = (v.i + 0x7FFFu + ((v.i >> 16) & 1u)) >> 16;
    return (u16)r;
}
// packed f32x2 -> bf16x2 (RNE), 1 VALU instruction (T12 recipe)
__device__ __forceinline__ u32 cvtpk(float lo, float hi) {
    u32 r; asm("v_cvt_pk_bf16_f32 %0, %1, %2" : "=v"(r) : "v"(lo), "v"(hi));
    return r;
}
// async global->LDS, 16B per lane. HW dest = wave-uniform base + lane*16.
__device__ __forceinline__ void gload16(const void* g, void* l) {
    __builtin_amdgcn_global_load_lds(
        (const __attribute__((address_space(1))) u32*)g,
        (__attribute__((address_space(3))) u32*)l, 16, 0, 0);
}

constexpr int N = 4096;
constexpr int Cc = 128;
constexpr int Fc = 128;
constexpr int BATCH = 4;
constexpr int NT = N / 128;     // 32 key tiles of 128 keys

constexpr int XS_STRIDE = 136;
constexpr int WT_STRIDE = 136;
constexpr int OM_STRIDE = 130;  // epilogue merge rows (f32): 2-way banks = free

// Q projection scale: (1/sqrt(128)) * log2(e)  -> softmax runs in exp2 domain
#define QSCALE 0.12751744750f

// ---------------------------------------------------------------------------
// W pre-transpose: Wt[which][f][c] (bf16). grid 3 x 256.
// ---------------------------------------------------------------------------
__global__ __launch_bounds__(256) void wtrans_kernel(
    const float* __restrict__ Wq, const float* __restrict__ Wk,
    const float* __restrict__ Wv, u16* __restrict__ WtG)
{
    __shared__ __align__(16) u16 Wl[128 * 132];  // [c][f]
    const int tid = threadIdx.x;
    const int which = blockIdx.x;
    const float* W = which == 0 ? Wq : (which == 1 ? Wk : Wv);
#pragma unroll
    for (int it = 0; it < 16; ++it) {
        int idx4 = tid + it * 256; int e0 = idx4 * 4;
        int c = e0 >> 7, f = e0 & 127;
        float4 wv = *(const float4*)(W + e0);
        u16x4 h; h[0] = f2b(wv.x); h[1] = f2b(wv.y); h[2] = f2b(wv.z); h[3] = f2b(wv.w);
        *(u16x4*)&Wl[c * 132 + f] = h;
    }
    __syncthreads();
    u16* out = WtG + which * 16384;
#pragma unroll
    for (int it = 0; it < 8; ++it) {
        int idx8 = tid + it * 256; int e0 = idx8 * 8;
        int f = e0 >> 7, c = e0 & 127;
        u16x8 h;
#pragma unroll
        for (int j = 0; j < 8; ++j) h[j] = Wl[(c + j) * 132 + f];
        *(u16x8*)(out + e0) = h;
    }
}

// ---------------------------------------------------------------------------
// Projection (fp32 X, bf16 Wt -> bf16 workspace). grid (64,3,4) x 256.
// Q: linear [b][m][f], pre-scaled by QSCALE.
// K: FRAGMENT-MAJOR  K_fm[b][kgrp=key>>5][kk=c>>4][lane][8]
//      lane = ((c>>3)&1)*32 + (key&31), elem j = c&7
// Vt: FRAGMENT-MAJOR V_fm[b][kgrp=key>>5][(ch>>5)*2 + ((key>>4)&1)][lane][8]
//      lane = ((key>>3)&1)*32 + (ch&31), elem j = key&7
// Both are CONTIGUOUS 32 KB per 128-key tile -> global_load_lds with linear
// dest; attn readback = base + lane*16B, conflict-free by construction.
// ---------------------------------------------------------------------------
__global__ __launch_bounds__(256) void proj_kernel(
    const float* __restrict__ q_in, const float* __restrict__ kv_in,
    const u16* __restrict__ WtG,
    const float* __restrict__ bq, const float* __restrict__ bk,
    const float* __restrict__ bv,
    u16* __restrict__ Qw, u16* __restrict__ Kw, u16* __restrict__ Vtw)
{
    __shared__ __align__(16) u16 Xs[64 * XS_STRIDE];   // [m][c] bf16
    __shared__ __align__(16) u16 Wt[128 * WT_STRIDE];  // [f][c] bf16

    const int tid = threadIdx.x;
    const int which = blockIdx.y;
    const int b = blockIdx.z;
    const int m0 = blockIdx.x * 64;

    const float* X = (which == 0 ? q_in : kv_in) + ((size_t)b * N + m0) * Cc;
    const u16* Wsrc = WtG + which * 16384;
    const float* bias = which == 0 ? bq : (which == 1 ? bk : bv);

#pragma unroll
    for (int it = 0; it < 8; ++it) {
        int idx4 = tid + it * 256; int e0 = idx4 * 4;
        int r = e0 >> 7, c = e0 & 127;
        float4 xv = *(const float4*)(X + e0);
        u16x4 h; h[0] = f2b(xv.x); h[1] = f2b(xv.y); h[2] = f2b(xv.z); h[3] = f2b(xv.w);
        *(u16x4*)&Xs[r * XS_STRIDE + c] = h;
    }
#pragma unroll
    for (int it = 0; it < 8; ++it) {
        int idx8 = tid + it * 256; int e0 = idx8 * 8;
        int f = e0 >> 7, c = e0 & 127;
        *(u16x8*)&Wt[f * WT_STRIDE + c] = *(const u16x8*)(Wsrc + e0);
    }
    __syncthreads();

    const int lane = tid & 63;
    const int w = tid >> 6;
    const int n16 = lane & 15;
    const int quad = lane >> 4;

    if (which < 2) {
        bf16x8 ax[4];
#pragma unroll
        for (int kk = 0; kk < 4; ++kk)
            ax[kk] = *(const bf16x8*)&Xs[(w * 16 + n16) * XS_STRIDE + kk * 32 + quad * 8];
        const float scale = (which == 0) ? QSCALE : 1.0f;
#pragma unroll
        for (int ft = 0; ft < 8; ++ft) {
            f32x4 acc = {0.f, 0.f, 0.f, 0.f};
#pragma unroll
            for (int kk = 0; kk < 4; ++kk) {
                bf16x8 bw = *(const bf16x8*)&Wt[(ft * 16 + n16) * WT_STRIDE + kk * 32 + quad * 8];
                acc = MFMA16(ax[kk], bw, acc);
            }
            float bias_f = bias[ft * 16 + n16];
#pragma unroll
            for (int r = 0; r < 4; ++r) {
                int row = m0 + w * 16 + quad * 4 + r;   // token index
                int f = ft * 16 + n16;                   // channel
                u16 val = f2b((acc[r] + bias_f) * scale);
                if (which == 0) {
                    Qw[((size_t)b * N + row) * Fc + f] = val;
                } else {
                    // K fragment-major
                    int kgrp = row >> 5, l31r = row & 31;
                    int kk2 = f >> 4, hig = (f >> 3) & 1, jj = f & 7;
                    Kw[((size_t)b * 1024 + kgrp * 8 + kk2) * 512
                       + (hig * 32 + l31r) * 8 + jj] = val;
                }
            }
        }
    } else {
#pragma unroll
        for (int ft2 = 0; ft2 < 2; ++ft2) {
            int ftg = w * 2 + ft2;
            bf16x8 aw[4];
#pragma unroll
            for (int kk = 0; kk < 4; ++kk)
                aw[kk] = *(const bf16x8*)&Wt[(ftg * 16 + n16) * WT_STRIDE + kk * 32 + quad * 8];
            float bias4[4];
#pragma unroll
            for (int r = 0; r < 4; ++r) bias4[r] = bias[ftg * 16 + quad * 4 + r];
#pragma unroll
            for (int nt = 0; nt < 4; ++nt) {
                f32x4 acc = {0.f, 0.f, 0.f, 0.f};
#pragma unroll
                for (int kk = 0; kk < 4; ++kk) {
                    bf16x8 bx = *(const bf16x8*)&Xs[(nt * 16 + n16) * XS_STRIDE + kk * 32 + quad * 8];
                    acc = MFMA16(aw[kk], bx, acc);
                }
#pragma unroll
                for (int r = 0; r < 4; ++r) {
                    int fg = ftg * 16 + quad * 4 + r;   // channel
                    int rowg = m0 + nt * 16 + n16;      // key
                    // V fragment-major
                    int kgrp = rowg >> 5, ks = (rowg >> 4) & 1;
                    int hig = (rowg >> 3) & 1, jj = rowg & 7;
                    int cb = fg >> 5, l31r = fg & 31;
                    Vtw[((size_t)b * 1024 + kgrp * 8 + cb * 2 + ks) * 512
                        + (hig * 32 + l31r) * 8 + jj] = f2b(acc[r] + bias4[r]);
                }
            }
        }
    }
}

// ---------------------------------------------------------------------------
// Flash attention, 32x32 MFMA, in-register P (cvt_pk + permlane32_swap).
// K AND V both staged per tile via global_load_lds of their CONTIGUOUS
// frag-major 32 KB tiles (one 64 KB DMA stream, linear dest). All LDS reads
// are base + lane*16B -> conflict-free by construction. No register
// double-buffers (frees ~64 VGPR vs r5/r7). One barrier per tile; the
// vmcnt drain covers DMA issued one full COMPUTE (~2000 cy) earlier.
// 512 threads = 8 waves = 2 q-groups(32 rows) x 4 key-groups(32 keys).
// grid (64, 4), 1 block/CU. XCD-swizzled: one batch per XCD (K+V L2-local).
// ---------------------------------------------------------------------------
__global__ __launch_bounds__(512, 2) void attn_kernel(
    const u16* __restrict__ Qw, const u16* __restrict__ Kw,
    const u16* __restrict__ Vtw, float* __restrict__ out)
{
    __shared__ __align__(16) char smem[134144];
    // double buffer: each 64 KB = [0,16384) K tile u16, [16384,32768) V tile
    u16* const B0 = (u16*)smem;
    u16* const B1 = (u16*)(smem + 65536);

    const int tid = threadIdx.x;
    // XCD-aware remap: blocks with equal (id&7) share a batch.
    const int id = blockIdx.x + 64 * blockIdx.y;
    const int b = (id >> 1) & 3;
    const int q0 = (((id & 1) << 5) + (id >> 3)) << 6;

    const int lane = tid & 63;
    const int w = tid >> 6;      // 0..7
    const int kg = w & 3;        // 32-key group within 128-key tile
    const int qg = w >> 2;       // 32-row q group within 64-row block
    const int l31 = lane & 31;
    const int hi = lane >> 5;

    // ---- Q fragments (B-operand of swapped QK^T), held for whole loop
    bf16x8 aq[8];
    {
        const u16* qp = Qw + ((size_t)b * N + q0 + qg * 32 + l31) * Cc + hi * 8;
#pragma unroll
        for (int kk = 0; kk < 8; ++kk) aq[kk] = *(const bf16x8*)(qp + kk * 16);
    }

    // frag-major tile bases; per-tile stride = 4 kgrp * 8 grp * 512 = 16384 u16
    const u16* const Ktile = Kw + (size_t)b * 1024 * 512;
    const u16* const Vtile = Vtw + (size_t)b * 1024 * 512;
    // this wave's read offsets inside a staged 32 KB tile (u16 units)
    const int kro = kg * 4096 + lane * 8;   // + kk*512
    const int vro = kg * 4096 + lane * 8;   // + (cb*2+ks)*512

    f32x16 o[4];
#pragma unroll
    for (int cb = 0; cb < 4; ++cb)
#pragma unroll
        for (int i = 0; i < 16; ++i) o[cb][i] = 0.f;
    float lloc = 0.f;

    int ci[4];
#pragma unroll
    for (int it = 0; it < 4; ++it) ci[it] = tid + it * 512;

    auto STAGE = [&](u16* bd, int t) {
        const u16* ksrc = Ktile + (size_t)t * 16384;   // contiguous 32 KB
        const u16* vsrc = Vtile + (size_t)t * 16384;   // contiguous 32 KB
#pragma unroll
        for (int it = 0; it < 4; ++it)
            gload16(ksrc + ci[it] * 8, bd + ci[it] * 8);
#pragma unroll
        for (int it = 0; it < 4; ++it)
            gload16(vsrc + ci[it] * 8, bd + 16384 + ci[it] * 8);
    };

    auto COMPUTE = [&](const u16* buf) {
        const u16* Ksb = buf;
        const u16* Vsb = buf + 16384;
        // S^T = K . Q^T over this wave's 32 keys: D[key][q], col=q=l31
        f32x16 st;
#pragma unroll
        for (int i = 0; i < 16; ++i) st[i] = 0.f;
        __builtin_amdgcn_s_setprio(1);
#pragma unroll
        for (int kk = 0; kk < 8; ++kk) {
            bf16x8 ak = *(const bf16x8*)(Ksb + kro + kk * 512);
            st = MFMA32(ak, aq[kk], st);
        }
        __builtin_amdgcn_s_setprio(0);
        // p = 2^s (Q pre-scaled by log2e); reg i = key (i&3)+8*(i>>2)+4*hi (+16 for i>=8)
        float p[16];
#pragma unroll
        for (int i = 0; i < 16; ++i) p[i] = exp2f(st[i]);
        lloc += ((((p[0] + p[1]) + (p[2] + p[3])) + ((p[4] + p[5]) + (p[6] + p[7])))
               + (((p[8] + p[9]) + (p[10] + p[11])) + ((p[12] + p[13]) + (p[14] + p[15]))));
        // pack bf16 pairs + permlane32_swap -> PV B-fragments (P^T), no LDS
        bf16x8 pb[2];
#pragma unroll
        for (int ks = 0; ks < 2; ++ks) {
            u32 a0 = cvtpk(p[ks * 8 + 0], p[ks * 8 + 1]);
            u32 a1 = cvtpk(p[ks * 8 + 2], p[ks * 8 + 3]);
            u32 a2 = cvtpk(p[ks * 8 + 4], p[ks * 8 + 5]);
            u32 a3 = cvtpk(p[ks * 8 + 6], p[ks * 8 + 7]);
            auto s02 = __builtin_amdgcn_permlane32_swap(a0, a2, false, false);
            auto s13 = __builtin_amdgcn_permlane32_swap(a1, a3, false, false);
            union { u32 u[4]; bf16x8 v; } bb;
            bb.u[0] = s02[0]; bb.u[1] = s13[0]; bb.u[2] = s02[1]; bb.u[3] = s13[1];
            pb[ks] = bb.v;
        }
        // O^T += Vt . P^T : D[ch][q]; A = contiguous b128 reads of staged V
        __builtin_amdgcn_s_setprio(1);
#pragma unroll
        for (int cb = 0; cb < 4; ++cb) {
            bf16x8 av0 = *(const bf16x8*)(Vsb + vro + (cb * 2 + 0) * 512);
            bf16x8 av1 = *(const bf16x8*)(Vsb + vro + (cb * 2 + 1) * 512);
            o[cb] = MFMA32(av0, pb[0], o[cb]);
            o[cb] = MFMA32(av1, pb[1], o[cb]);
        }
        __builtin_amdgcn_s_setprio(0);
    };

    STAGE(B0, 0);
    __syncthreads();                      // tile 0 resident
    for (int t = 0; t < NT; t += 2) {
        if (t + 1 < NT) STAGE(B1, t + 1); // full tile of latency cover
        COMPUTE(B0);                      // tile t
        __syncthreads();                  // tile t+1 resident; B0 free
        if (t + 2 < NT) STAGE(B0, t + 2);
        COMPUTE(B1);                      // tile t+1
        __syncthreads();
    }

    // ---- atomic-free merge: all 8 waves dump to private slot, then reduce
    float lv = lloc + __shfl_xor(lloc, 32);   // full l-partial for q=l31, this kg

    float* const Om = (float*)smem;            // [4 kg][64 q][OM_STRIDE] f32
    float* const Lm = (float*)(smem + 4 * 64 * OM_STRIDE * 4);  // [4 kg][64 q]

    const int qrow_w = qg * 32 + l31;          // 0..63 within block
    const int crow0 = 4 * hi;
    {
        float* dst = Om + (size_t)(kg * 64 + qrow_w) * OM_STRIDE;
#pragma unroll
        for (int cb = 0; cb < 4; ++cb)
#pragma unroll
            for (int i = 0; i < 16; ++i) {
                int ch = cb * 32 + (i & 3) + 8 * (i >> 2) + crow0;
                dst[ch] = o[cb][i];
            }
        if (hi == 0) Lm[kg * 64 + qrow_w] = lv;
    }
    __syncthreads();

    const int qrow = tid >> 3;                // 0..63
    const int ch0 = (tid & 7) * 16;
    const float lsum = Lm[qrow] + Lm[64 + qrow] + Lm[128 + qrow] + Lm[192 + qrow];
    const float linv = 1.0f / lsum;
    float* op = out + ((size_t)b * N + q0 + qrow) * Fc + ch0;
#pragma unroll
    for (int j4 = 0; j4 < 4; ++j4) {
        f32x4 v;
#pragma unroll
        for (int jj = 0; jj < 4; ++jj) {
            int ch = ch0 + j4 * 4 + jj;
            float s = Om[(size_t)(0 * 64 + qrow) * OM_STRIDE + ch]
                    + Om[(size_t)(1 * 64 + qrow) * OM_STRIDE + ch]
                    + Om[(size_t)(2 * 64 + qrow) * OM_STRIDE + ch]
                    + Om[(size_t)(3 * 64 + qrow) * OM_STRIDE + ch];
            v[jj] = s * linv;
        }
        *(f32x4*)(op + j4 * 4) = v;
    }
}

extern "C" void kernel_launch(void* const* d_in, const int* in_sizes, int n_in,
                              void* d_out, int out_size, void* d_ws, size_t ws_size,
                              hipStream_t stream) {
    (void)in_sizes; (void)n_in; (void)out_size; (void)ws_size;
    const float* q_in  = (const float*)d_in[0];
    const float* kv_in = (const float*)d_in[1];
    const float* Wq = (const float*)d_in[2];
    const float* bq = (const float*)d_in[3];
    const float* Wk = (const float*)d_in[4];
    const float* bk = (const float*)d_in[5];
    const float* Wv = (const float*)d_in[6];
    const float* bv = (const float*)d_in[7];

    const size_t qkv = (size_t)BATCH * N * Fc;
    u16* Qw  = (u16*)d_ws;          // [b][m][f] bf16, pre-scaled by QSCALE
    u16* Kw  = Qw + qkv;            // fragment-major K (1 MB/batch)
    u16* Vtw = Kw + qkv;            // fragment-major V^T (1 MB/batch)
    u16* WtG = Vtw + qkv;           // [3][f][c] bf16 pre-transposed weights

    wtrans_kernel<<<dim3(3), dim3(256), 0, stream>>>(Wq, Wk, Wv, WtG);
    proj_kernel<<<dim3(64, 3, BATCH), dim3(256), 0, stream>>>(
        q_in, kv_in, WtG, bq, bk, bv, Qw, Kw, Vtw);
    attn_kernel<<<dim3(64, BATCH), dim3(512), 0, stream>>>(
        Qw, Kw, Vtw, (float*)d_out);
}

// Round 9
// 134.611 us; speedup vs baseline: 1.4332x; 1.0020x over previous
//
#include <hip/hip_runtime.h>
#include <stdint.h>
#include <math.h>

typedef unsigned short u16;
typedef unsigned int u32;
typedef __bf16 bf16x8 __attribute__((ext_vector_type(8)));
typedef unsigned short u16x8 __attribute__((ext_vector_type(8)));
typedef unsigned short u16x4 __attribute__((ext_vector_type(4)));
typedef float f32x4 __attribute__((ext_vector_type(4)));
typedef float f32x16 __attribute__((ext_vector_type(16)));

#define MFMA16(a, b, c) __builtin_amdgcn_mfma_f32_16x16x32_bf16((a), (b), (c), 0, 0, 0)
#define MFMA32(a, b, c) __builtin_amdgcn_mfma_f32_32x32x16_bf16((a), (b), (c), 0, 0, 0)

__device__ __forceinline__ u16 f2b(float f) {
    union { unsigned int i; float f; } v; v.f = f;
    unsigned int r = (v.i + 0x7FFFu + ((v.i >> 16) & 1u)) >> 16;
    return (u16)r;
}
// packed f32x2 -> bf16x2 (RNE), 1 VALU instruction (T12 recipe)
__device__ __forceinline__ u32 cvtpk(float lo, float hi) {
    u32 r; asm("v_cvt_pk_bf16_f32 %0, %1, %2" : "=v"(r) : "v"(lo), "v"(hi));
    return r;
}
// async global->LDS, 16B per lane. HW dest = wave-uniform base + lane*16.
__device__ __forceinline__ void gload16(const void* g, void* l) {
    __builtin_amdgcn_global_load_lds(
        (const __attribute__((address_space(1))) u32*)g,
        (__attribute__((address_space(3))) u32*)l, 16, 0, 0);
}

constexpr int N = 4096;
constexpr int Cc = 128;
constexpr int Fc = 128;
constexpr int BATCH = 4;
constexpr int NT = N / 128;     // 32 key tiles of 128 keys

constexpr int XS_STRIDE = 136;
constexpr int WT_STRIDE = 136;
constexpr int KO_STRIDE = 136;  // repack tile [64 row][136] (aliases Xs; 16B-aligned rows)
constexpr int VO_STRIDE = 72;   // repack tile [128 ch][72]  (aliases Wt; 16B-aligned rows)
constexpr int OM_STRIDE = 130;  // epilogue merge rows (f32): 2-way banks = free

// Q projection scale: (1/sqrt(128)) * log2(e)  -> softmax runs in exp2 domain
#define QSCALE 0.12751744750f

// ---------------------------------------------------------------------------
// W pre-transpose: Wt[which][f][c] (bf16). grid 3 x 256.
// ---------------------------------------------------------------------------
__global__ __launch_bounds__(256) void wtrans_kernel(
    const float* __restrict__ Wq, const float* __restrict__ Wk,
    const float* __restrict__ Wv, u16* __restrict__ WtG)
{
    __shared__ __align__(16) u16 Wl[128 * 132];  // [c][f]
    const int tid = threadIdx.x;
    const int which = blockIdx.x;
    const float* W = which == 0 ? Wq : (which == 1 ? Wk : Wv);
#pragma unroll
    for (int it = 0; it < 16; ++it) {
        int idx4 = tid + it * 256; int e0 = idx4 * 4;
        int c = e0 >> 7, f = e0 & 127;
        float4 wv = *(const float4*)(W + e0);
        u16x4 h; h[0] = f2b(wv.x); h[1] = f2b(wv.y); h[2] = f2b(wv.z); h[3] = f2b(wv.w);
        *(u16x4*)&Wl[c * 132 + f] = h;
    }
    __syncthreads();
    u16* out = WtG + which * 16384;
#pragma unroll
    for (int it = 0; it < 8; ++it) {
        int idx8 = tid + it * 256; int e0 = idx8 * 8;
        int f = e0 >> 7, c = e0 & 127;
        u16x8 h;
#pragma unroll
        for (int j = 0; j < 8; ++j) h[j] = Wl[(c + j) * 132 + f];
        *(u16x8*)(out + e0) = h;
    }
}

// ---------------------------------------------------------------------------
// Projection (fp32 X, bf16 Wt -> bf16 workspace). grid (64,3,4) x 256.
// Q: linear [b][m][f], pre-scaled by QSCALE (direct stores, 32B segments).
// K: FRAGMENT-MAJOR  K_fm[b][kgrp=key>>5][kk=c>>4][(hig*32+l31)][8]
// Vt: FRAGMENT-MAJOR V_fm[b][kgrp=key>>5][(ch>>5)*2+((key>>4)&1)][...][8]
// K/V results are first dumped to an LDS repack tile (scalar writes, padded
// strides), then emitted as FULLY COALESCED u16x8 global stores: the
// frag-major output region of one block is a contiguous 16 KB range, and
// e = tid*8 + it*2048 walks it linearly (inverse map verified against the
// r8 scatter formula term-by-term).
// ---------------------------------------------------------------------------
__global__ __launch_bounds__(256) void proj_kernel(
    const float* __restrict__ q_in, const float* __restrict__ kv_in,
    const u16* __restrict__ WtG,
    const float* __restrict__ bq, const float* __restrict__ bk,
    const float* __restrict__ bv,
    u16* __restrict__ Qw, u16* __restrict__ Kw, u16* __restrict__ Vtw)
{
    __shared__ __align__(16) u16 Xs[64 * XS_STRIDE];   // [m][c] bf16
    __shared__ __align__(16) u16 Wt[128 * WT_STRIDE];  // [f][c] bf16

    const int tid = threadIdx.x;
    const int which = blockIdx.y;
    const int b = blockIdx.z;
    const int m0 = blockIdx.x * 64;

    const float* X = (which == 0 ? q_in : kv_in) + ((size_t)b * N + m0) * Cc;
    const u16* Wsrc = WtG + which * 16384;
    const float* bias = which == 0 ? bq : (which == 1 ? bk : bv);

#pragma unroll
    for (int it = 0; it < 8; ++it) {
        int idx4 = tid + it * 256; int e0 = idx4 * 4;
        int r = e0 >> 7, c = e0 & 127;
        float4 xv = *(const float4*)(X + e0);
        u16x4 h; h[0] = f2b(xv.x); h[1] = f2b(xv.y); h[2] = f2b(xv.z); h[3] = f2b(xv.w);
        *(u16x4*)&Xs[r * XS_STRIDE + c] = h;
    }
#pragma unroll
    for (int it = 0; it < 8; ++it) {
        int idx8 = tid + it * 256; int e0 = idx8 * 8;
        int f = e0 >> 7, c = e0 & 127;
        *(u16x8*)&Wt[f * WT_STRIDE + c] = *(const u16x8*)(Wsrc + e0);
    }
    __syncthreads();

    const int lane = tid & 63;
    const int w = tid >> 6;
    const int n16 = lane & 15;
    const int quad = lane >> 4;

    if (which < 2) {
        bf16x8 ax[4];
#pragma unroll
        for (int kk = 0; kk < 4; ++kk)
            ax[kk] = *(const bf16x8*)&Xs[(w * 16 + n16) * XS_STRIDE + kk * 32 + quad * 8];
        const float scale = (which == 0) ? QSCALE : 1.0f;
        if (which == 0) {
            // Q: direct stores (linear layout, 32B segments per row group)
#pragma unroll
            for (int ft = 0; ft < 8; ++ft) {
                f32x4 acc = {0.f, 0.f, 0.f, 0.f};
#pragma unroll
                for (int kk = 0; kk < 4; ++kk) {
                    bf16x8 bw = *(const bf16x8*)&Wt[(ft * 16 + n16) * WT_STRIDE + kk * 32 + quad * 8];
                    acc = MFMA16(ax[kk], bw, acc);
                }
                float bias_f = bias[ft * 16 + n16];
#pragma unroll
                for (int r = 0; r < 4; ++r) {
                    int row = m0 + w * 16 + quad * 4 + r;
                    Qw[((size_t)b * N + row) * Fc + ft * 16 + n16] =
                        f2b((acc[r] + bias_f) * scale);
                }
            }
        } else {
            // K: compute all results first (Xs stays live), then repack
            float accs[8][4];
            float biasf[8];
#pragma unroll
            for (int ft = 0; ft < 8; ++ft) {
                f32x4 acc = {0.f, 0.f, 0.f, 0.f};
#pragma unroll
                for (int kk = 0; kk < 4; ++kk) {
                    bf16x8 bw = *(const bf16x8*)&Wt[(ft * 16 + n16) * WT_STRIDE + kk * 32 + quad * 8];
                    acc = MFMA16(ax[kk], bw, acc);
                }
                biasf[ft] = bias[ft * 16 + n16];
#pragma unroll
                for (int r = 0; r < 4; ++r) accs[ft][r] = acc[r];
            }
            __syncthreads();               // all Xs/Wt reads done
            u16* const Ko = Xs;            // [64 row][KO_STRIDE]
#pragma unroll
            for (int ft = 0; ft < 8; ++ft)
#pragma unroll
                for (int r = 0; r < 4; ++r) {
                    int rl = w * 16 + quad * 4 + r;        // local row
                    int f = ft * 16 + n16;                 // channel
                    Ko[rl * KO_STRIDE + f] = f2b(accs[ft][r] + biasf[ft]);
                }
            __syncthreads();
            // coalesced frag-major emit: e = (lg*8+kk2)*512 + hig*256 + l31*8 + jj
            u16* const outK = Kw + ((size_t)b * 1024 + (m0 >> 5) * 8) * 512;
#pragma unroll
            for (int it = 0; it < 4; ++it) {
                int e = tid * 8 + it * 2048;
                int lg = e >> 12, rem = e & 4095;
                int kk2 = rem >> 9, rem2 = rem & 511;
                int hig = rem2 >> 8, l31v = (rem2 >> 3) & 31;
                int row_l = lg * 32 + l31v;
                int fbase = kk2 * 16 + hig * 8;
                *(u16x8*)(outK + e) = *(const u16x8*)&Ko[row_l * KO_STRIDE + fbase];
            }
        }
    } else {
        // V: compute all results (A=weights, B=X -> transposed output), repack
        float accs[2][4][4];
        float bias4[2][4];
#pragma unroll
        for (int ft2 = 0; ft2 < 2; ++ft2) {
            int ftg = w * 2 + ft2;
            bf16x8 aw[4];
#pragma unroll
            for (int kk = 0; kk < 4; ++kk)
                aw[kk] = *(const bf16x8*)&Wt[(ftg * 16 + n16) * WT_STRIDE + kk * 32 + quad * 8];
#pragma unroll
            for (int r = 0; r < 4; ++r) bias4[ft2][r] = bias[ftg * 16 + quad * 4 + r];
#pragma unroll
            for (int nt = 0; nt < 4; ++nt) {
                f32x4 acc = {0.f, 0.f, 0.f, 0.f};
#pragma unroll
                for (int kk = 0; kk < 4; ++kk) {
                    bf16x8 bx = *(const bf16x8*)&Xs[(nt * 16 + n16) * XS_STRIDE + kk * 32 + quad * 8];
                    acc = MFMA16(aw[kk], bx, acc);
                }
#pragma unroll
                for (int r = 0; r < 4; ++r) accs[ft2][nt][r] = acc[r];
            }
        }
        __syncthreads();                   // all Xs/Wt reads done
        u16* const Vo = Wt;                // [128 ch][VO_STRIDE]
#pragma unroll
        for (int ft2 = 0; ft2 < 2; ++ft2)
#pragma unroll
            for (int nt = 0; nt < 4; ++nt)
#pragma unroll
                for (int r = 0; r < 4; ++r) {
                    int fg = (w * 2 + ft2) * 16 + quad * 4 + r;  // channel
                    int kl = nt * 16 + n16;                      // local key
                    Vo[fg * VO_STRIDE + kl] = f2b(accs[ft2][nt][r] + bias4[ft2][r]);
                }
        __syncthreads();
        // coalesced frag-major emit: e = (lg*8+cb*2+ks)*512 + hig*256 + l31*8 + jj
        u16* const outV = Vtw + ((size_t)b * 1024 + (m0 >> 5) * 8) * 512;
#pragma unroll
        for (int it = 0; it < 4; ++it) {
            int e = tid * 8 + it * 2048;
            int lg = e >> 12, rem = e & 4095;
            int grp = rem >> 9, rem2 = rem & 511;
            int cb = grp >> 1, ks = grp & 1;
            int hig = rem2 >> 8, l31v = (rem2 >> 3) & 31;
            int ch = cb * 32 + l31v;
            int kbase = lg * 32 + ks * 16 + hig * 8;
            *(u16x8*)(outV + e) = *(const u16x8*)&Vo[ch * VO_STRIDE + kbase];
        }
    }
}

// ---------------------------------------------------------------------------
// Flash attention (identical to round-8 kernel, 58.4 us measured).
// ---------------------------------------------------------------------------
__global__ __launch_bounds__(512, 2) void attn_kernel(
    const u16* __restrict__ Qw, const u16* __restrict__ Kw,
    const u16* __restrict__ Vtw, float* __restrict__ out)
{
    __shared__ __align__(16) char smem[134144];
    u16* const B0 = (u16*)smem;
    u16* const B1 = (u16*)(smem + 65536);

    const int tid = threadIdx.x;
    const int id = blockIdx.x + 64 * blockIdx.y;
    const int b = (id >> 1) & 3;
    const int q0 = (((id & 1) << 5) + (id >> 3)) << 6;

    const int lane = tid & 63;
    const int w = tid >> 6;
    const int kg = w & 3;
    const int qg = w >> 2;
    const int l31 = lane & 31;
    const int hi = lane >> 5;

    bf16x8 aq[8];
    {
        const u16* qp = Qw + ((size_t)b * N + q0 + qg * 32 + l31) * Cc + hi * 8;
#pragma unroll
        for (int kk = 0; kk < 8; ++kk) aq[kk] = *(const bf16x8*)(qp + kk * 16);
    }

    const u16* const Ktile = Kw + (size_t)b * 1024 * 512;
    const u16* const Vtile = Vtw + (size_t)b * 1024 * 512;
    const int kro = kg * 4096 + lane * 8;
    const int vro = kg * 4096 + lane * 8;

    f32x16 o[4];
#pragma unroll
    for (int cb = 0; cb < 4; ++cb)
#pragma unroll
        for (int i = 0; i < 16; ++i) o[cb][i] = 0.f;
    float lloc = 0.f;

    int ci[4];
#pragma unroll
    for (int it = 0; it < 4; ++it) ci[it] = tid + it * 512;

    auto STAGE = [&](u16* bd, int t) {
        const u16* ksrc = Ktile + (size_t)t * 16384;
        const u16* vsrc = Vtile + (size_t)t * 16384;
#pragma unroll
        for (int it = 0; it < 4; ++it)
            gload16(ksrc + ci[it] * 8, bd + ci[it] * 8);
#pragma unroll
        for (int it = 0; it < 4; ++it)
            gload16(vsrc + ci[it] * 8, bd + 16384 + ci[it] * 8);
    };

    auto COMPUTE = [&](const u16* buf) {
        const u16* Ksb = buf;
        const u16* Vsb = buf + 16384;
        f32x16 st;
#pragma unroll
        for (int i = 0; i < 16; ++i) st[i] = 0.f;
        __builtin_amdgcn_s_setprio(1);
#pragma unroll
        for (int kk = 0; kk < 8; ++kk) {
            bf16x8 ak = *(const bf16x8*)(Ksb + kro + kk * 512);
            st = MFMA32(ak, aq[kk], st);
        }
        __builtin_amdgcn_s_setprio(0);
        float p[16];
#pragma unroll
        for (int i = 0; i < 16; ++i) p[i] = exp2f(st[i]);
        lloc += ((((p[0] + p[1]) + (p[2] + p[3])) + ((p[4] + p[5]) + (p[6] + p[7])))
               + (((p[8] + p[9]) + (p[10] + p[11])) + ((p[12] + p[13]) + (p[14] + p[15]))));
        bf16x8 pb[2];
#pragma unroll
        for (int ks = 0; ks < 2; ++ks) {
            u32 a0 = cvtpk(p[ks * 8 + 0], p[ks * 8 + 1]);
            u32 a1 = cvtpk(p[ks * 8 + 2], p[ks * 8 + 3]);
            u32 a2 = cvtpk(p[ks * 8 + 4], p[ks * 8 + 5]);
            u32 a3 = cvtpk(p[ks * 8 + 6], p[ks * 8 + 7]);
            auto s02 = __builtin_amdgcn_permlane32_swap(a0, a2, false, false);
            auto s13 = __builtin_amdgcn_permlane32_swap(a1, a3, false, false);
            union { u32 u[4]; bf16x8 v; } bb;
            bb.u[0] = s02[0]; bb.u[1] = s13[0]; bb.u[2] = s02[1]; bb.u[3] = s13[1];
            pb[ks] = bb.v;
        }
        __builtin_amdgcn_s_setprio(1);
#pragma unroll
        for (int cb = 0; cb < 4; ++cb) {
            bf16x8 av0 = *(const bf16x8*)(Vsb + vro + (cb * 2 + 0) * 512);
            bf16x8 av1 = *(const bf16x8*)(Vsb + vro + (cb * 2 + 1) * 512);
            o[cb] = MFMA32(av0, pb[0], o[cb]);
            o[cb] = MFMA32(av1, pb[1], o[cb]);
        }
        __builtin_amdgcn_s_setprio(0);
    };

    STAGE(B0, 0);
    __syncthreads();
    for (int t = 0; t < NT; t += 2) {
        if (t + 1 < NT) STAGE(B1, t + 1);
        COMPUTE(B0);
        __syncthreads();
        if (t + 2 < NT) STAGE(B0, t + 2);
        COMPUTE(B1);
        __syncthreads();
    }

    float lv = lloc + __shfl_xor(lloc, 32);

    float* const Om = (float*)smem;
    float* const Lm = (float*)(smem + 4 * 64 * OM_STRIDE * 4);

    const int qrow_w = qg * 32 + l31;
    const int crow0 = 4 * hi;
    {
        float* dst = Om + (size_t)(kg * 64 + qrow_w) * OM_STRIDE;
#pragma unroll
        for (int cb = 0; cb < 4; ++cb)
#pragma unroll
            for (int i = 0; i < 16; ++i) {
                int ch = cb * 32 + (i & 3) + 8 * (i >> 2) + crow0;
                dst[ch] = o[cb][i];
            }
        if (hi == 0) Lm[kg * 64 + qrow_w] = lv;
    }
    __syncthreads();

    const int qrow = tid >> 3;
    const int ch0 = (tid & 7) * 16;
    const float lsum = Lm[qrow] + Lm[64 + qrow] + Lm[128 + qrow] + Lm[192 + qrow];
    const float linv = 1.0f / lsum;
    float* op = out + ((size_t)b * N + q0 + qrow) * Fc + ch0;
#pragma unroll
    for (int j4 = 0; j4 < 4; ++j4) {
        f32x4 v;
#pragma unroll
        for (int jj = 0; jj < 4; ++jj) {
            int ch = ch0 + j4 * 4 + jj;
            float s = Om[(size_t)(0 * 64 + qrow) * OM_STRIDE + ch]
                    + Om[(size_t)(1 * 64 + qrow) * OM_STRIDE + ch]
                    + Om[(size_t)(2 * 64 + qrow) * OM_STRIDE + ch]
                    + Om[(size_t)(3 * 64 + qrow) * OM_STRIDE + ch];
            v[jj] = s * linv;
        }
        *(f32x4*)(op + j4 * 4) = v;
    }
}

extern "C" void kernel_launch(void* const* d_in, const int* in_sizes, int n_in,
                              void* d_out, int out_size, void* d_ws, size_t ws_size,
                              hipStream_t stream) {
    (void)in_sizes; (void)n_in; (void)out_size; (void)ws_size;
    const float* q_in  = (const float*)d_in[0];
    const float* kv_in = (const float*)d_in[1];
    const float* Wq = (const float*)d_in[2];
    const float* bq = (const float*)d_in[3];
    const float* Wk = (const float*)d_in[4];
    const float* bk = (const float*)d_in[5];
    const float* Wv = (const float*)d_in[6];
    const float* bv = (const float*)d_in[7];

    const size_t qkv = (size_t)BATCH * N * Fc;
    u16* Qw  = (u16*)d_ws;          // [b][m][f] bf16, pre-scaled by QSCALE
    u16* Kw  = Qw + qkv;            // fragment-major K (1 MB/batch)
    u16* Vtw = Kw + qkv;            // fragment-major V^T (1 MB/batch)
    u16* WtG = Vtw + qkv;           // [3][f][c] bf16 pre-transposed weights

    wtrans_kernel<<<dim3(3), dim3(256), 0, stream>>>(Wq, Wk, Wv, WtG);
    proj_kernel<<<dim3(64, 3, BATCH), dim3(256), 0, stream>>>(
        q_in, kv_in, WtG, bq, bk, bv, Qw, Kw, Vtw);
    attn_kernel<<<dim3(64, BATCH), dim3(512), 0, stream>>>(
        Qw, Kw, Vtw, (float*)d_out);
}